// Round 15
// baseline (413.204 us; speedup 1.0000x reference)
//
#include <hip/hip_runtime.h>

#define EPS 1e-5f
#define KK 27

typedef __bf16 bf16x8 __attribute__((ext_vector_type(8)));
typedef float f32x4 __attribute__((ext_vector_type(4)));

__device__ __forceinline__ unsigned short f2bf(float f) {
    union { float f; unsigned u; } v; v.f = f;
    unsigned r = v.u + 0x7fffu + ((v.u >> 16) & 1u);  // round-to-nearest-even
    return (unsigned short)(r >> 16);
}
__device__ __forceinline__ float bf2f(unsigned short h) {
    union { unsigned u; float f; } v; v.u = ((unsigned)h) << 16; return v.f;
}

__device__ __forceinline__ f32x4 mfma16(bf16x8 a, bf16x8 b, f32x4 c) {
    return __builtin_amdgcn_mfma_f32_16x16x32_bf16(a, b, c, 0, 0, 0);
}

// bijective XCD-chunked swizzle: spatially-consecutive blocks -> same XCD
__device__ __forceinline__ long swz_bid(long bid, long nwg) {
    long q = nwg >> 3, r = nwg & 7;
    long x = bid & 7, o = bid >> 3;
    long base = (x < r) ? x * (q + 1) : r * (q + 1) + (x - r) * q;
    return base + o;
}

// ---------------- spatial sort by pool_seg: hist -> scan -> scatter ----------------
__global__ void hist_seg(const int* __restrict__ seg, long n, int* __restrict__ cnt) {
    long i = (long)blockIdx.x * 256 + threadIdx.x;
    if (i < n) atomicAdd(&cnt[seg[i]], 1);
}

__global__ void scan_block256(const int* __restrict__ cnt, int np,
                              int* __restrict__ excl, int* __restrict__ bsum) {
    __shared__ int s[256];
    int i = blockIdx.x * 256 + threadIdx.x;
    int v = (i < np) ? cnt[i] : 0;
    s[threadIdx.x] = v; __syncthreads();
    #pragma unroll
    for (int d = 1; d < 256; d <<= 1) {
        int t = (threadIdx.x >= d) ? s[threadIdx.x - d] : 0;
        __syncthreads();
        s[threadIdx.x] += t;
        __syncthreads();
    }
    if (i < np) excl[i] = s[threadIdx.x] - v;
    if (threadIdx.x == 255) bsum[blockIdx.x] = s[255];
}

__global__ void scan_tops256(int* __restrict__ bsum, int nb) {
    __shared__ int s[256];
    int v = (threadIdx.x < nb) ? bsum[threadIdx.x] : 0;
    s[threadIdx.x] = v; __syncthreads();
    #pragma unroll
    for (int d = 1; d < 256; d <<= 1) {
        int t = (threadIdx.x >= d) ? s[threadIdx.x - d] : 0;
        __syncthreads();
        s[threadIdx.x] += t;
        __syncthreads();
    }
    if (threadIdx.x < nb) bsum[threadIdx.x] = s[threadIdx.x] - v;  // exclusive
}

__global__ void scan_add(int* __restrict__ excl, const int* __restrict__ bsum, int np) {
    int i = blockIdx.x * 256 + threadIdx.x;
    if (i < np) excl[i] += bsum[blockIdx.x];
}

__global__ void scatter_perm(const int* __restrict__ seg, long n, int* __restrict__ ofs,
                             int* __restrict__ perm, int* __restrict__ inv) {
    long i = (long)blockIdx.x * 256 + threadIdx.x;
    if (i >= n) return;
    int p = atomicAdd(&ofs[seg[i]], 1);
    perm[p] = (int)i;
    inv[i] = p;
}

__global__ void permute_f32(const float* __restrict__ src, const int* __restrict__ perm,
                            float* __restrict__ dst, long n) {
    long i = (long)blockIdx.x * 256 + threadIdx.x;
    if (i < n) dst[i] = src[perm[i]];
}

// ---------------- map build: idxG[block][k][row&31] ----------------
__global__ void fill_i32(int* __restrict__ p, long tot, int val) {
    long i = (long)blockIdx.x * blockDim.x + threadIdx.x;
    if (i < tot) p[i] = val;
}

// permuted space (layer 1/2): out-position and in-row both remapped by inv
__global__ void invert_map_p(const int* __restrict__ km_in, const int* __restrict__ km_out,
                             const int* __restrict__ inv, int* __restrict__ idxG,
                             int M, int nrows) {
    long i = (long)blockIdx.x * blockDim.x + threadIdx.x;
    if (i >= (long)KK * M) return;
    int k = (int)(i / M);
    int ki = km_in[i];
    if (ki < nrows) {
        int po = inv[km_out[i]];
        idxG[(long)(po >> 5) * 1024 + k * 32 + (po & 31)] = inv[ki];
    }
}

__global__ void invert_map_g(const int* __restrict__ km_in, const int* __restrict__ km_out,
                             int* __restrict__ idxG, int M, int nrows) {
    long i = (long)blockIdx.x * blockDim.x + threadIdx.x;
    if (i >= (long)KK * M) return;
    int k = (int)(i / M);
    int ki = km_in[i];
    if (ki < nrows) {
        int ko = km_out[i];
        idxG[(long)(ko >> 5) * 1024 + k * 32 + (ko & 31)] = ki;
    }
}

// ---------------- weight prep ----------------
__global__ void wt_frag(const float* __restrict__ W, unsigned short* __restrict__ Wt,
                        int Cin, int Cout) {
    long i = (long)blockIdx.x * blockDim.x + threadIdx.x;
    long tot = (long)KK * Cin * Cout;
    if (i >= tot) return;
    int k  = (int)(i / (Cin * Cout));
    int r  = (int)(i % (Cin * Cout));
    int ci = r / Cout, co = r % Cout;
    int t = co >> 4, m16 = co & 15;
    int s = ci >> 5, quad = (ci >> 3) & 3, j = ci & 7;
    int lane = quad * 16 + m16;
    long off = ((((long)k * (Cout >> 4) + t) * 2 + s) * 64 + lane) * 8 + j;
    Wt[off] = f2bf(W[i]);
}

__global__ void w1t_bf16(const float* __restrict__ W1, unsigned short* __restrict__ W1t) {
    int i = blockIdx.x * blockDim.x + threadIdx.x;
    if (i >= 64 * 32) return;
    int c = i / 32, kk = i % 32;
    W1t[i] = (kk < KK) ? f2bf(W1[kk * 64 + c]) : (unsigned short)0;
}

// ---------------- partial-stats reduction: sum 64 block-rows, few spread atomics ----
__global__ void stats_part(const float* __restrict__ p, int nblk, int width,
                           float* __restrict__ out) {
    int c = threadIdx.x;               // < width
    int b0 = blockIdx.x * 64;
    int b1 = b0 + 64 < nblk ? b0 + 64 : nblk;
    float acc = 0.f;
    for (int b = b0; b < b1; ++b) acc += p[(long)b * width + c];
    atomicAdd(&out[c], acc);
}

// ---------------- conv1 gather-MFMA (1->64): block-partial stats, coalesced C ----
__global__ __launch_bounds__(256, 2) void conv1_mfma(const float* __restrict__ feats,
                                                     const unsigned short* __restrict__ W1t,
                                                     const int* __restrict__ idxG, int n,
                                                     unsigned short* __restrict__ out,
                                                     float* __restrict__ partial) {
    __shared__ __align__(16) int lidx[4][1024];
    __shared__ float sstat[4][128];
    int tid = threadIdx.x;
    int wave = tid >> 6, lane = tid & 63;
    int m16 = lane & 15, quad = lane >> 4;
    long tile = (long)blockIdx.x * 4 + wave;
    long j0 = tile * 32;
    bool valid = (j0 < n);
    long jb = valid ? (j0 >> 5) : 0;

    // stage this wave's 27x32 idx block (4KB, one coalesced wave-load x4)
    {
        const int* src = idxG + jb * 1024;
        #pragma unroll
        for (int i = 0; i < 4; ++i)
            __builtin_amdgcn_global_load_lds(
                (const __attribute__((address_space(1))) unsigned*)(src + i * 256 + lane * 4),
                (__attribute__((address_space(3))) unsigned*)(&lidx[wave][i * 256]),
                16, 0, 0);
    }
    asm volatile("s_waitcnt vmcnt(0)" ::: "memory");
    const int* lip = &lidx[wave][0];

    int idx[2][8];
    #pragma unroll
    for (int i = 0; i < 8; ++i) {
        int kk = quad * 8 + i;
        bool kv = (kk < KK);
        idx[0][i] = (valid && kv) ? lip[kk * 32 + m16] : n;
        idx[1][i] = (valid && kv) ? lip[kk * 32 + 16 + m16] : n;
    }
    float f[2][8];
    #pragma unroll
    for (int i = 0; i < 8; ++i)
        #pragma unroll
        for (int t2 = 0; t2 < 2; ++t2) {
            int r = idx[t2][i];
            f[t2][i] = (r < n) ? feats[r] : 0.f;
        }

    union { bf16x8 v; unsigned short s[8]; } a[2];
    #pragma unroll
    for (int t2 = 0; t2 < 2; ++t2)
        #pragma unroll
        for (int i = 0; i < 8; ++i) a[t2].s[i] = f2bf(f[t2][i]);

    f32x4 acc[2][4];
    #pragma unroll
    for (int t2 = 0; t2 < 2; ++t2)
        #pragma unroll
        for (int t = 0; t < 4; ++t) acc[t2][t] = (f32x4){0.f, 0.f, 0.f, 0.f};

    const unsigned short* wb = W1t + quad * 8;
    #pragma unroll
    for (int t = 0; t < 4; ++t) {
        bf16x8 b = *(const bf16x8*)(wb + (t * 16 + m16) * 32);
        acc[0][t] = mfma16(a[0].v, b, acc[0][t]);
        acc[1][t] = mfma16(a[1].v, b, acc[1][t]);
    }

    // staged coalesced C-store: acc -> LDS (alias idx area, dead now) -> 128B rows
    asm volatile("" ::: "memory");
    unsigned short* sb = (unsigned short*)&lidx[wave][0];   // 4KB = 32 rows x 64 bf16
    #pragma unroll
    for (int t2 = 0; t2 < 2; ++t2)
        #pragma unroll
        for (int t = 0; t < 4; ++t)
            #pragma unroll
            for (int r2 = 0; r2 < 4; ++r2)
                sb[(t2 * 16 + quad * 4 + r2) * 64 + t * 16 + m16] = f2bf(acc[t2][t][r2]);
    asm volatile("s_waitcnt lgkmcnt(0)" ::: "memory");
    #pragma unroll
    for (int i = 0; i < 4; ++i) {
        int row = i * 8 + (lane >> 3);
        long rr = j0 + row;
        if (rr < n)
            *(bf16x8*)(out + rr * 64 + (lane & 7) * 8) =
                *(const bf16x8*)(sb + row * 64 + (lane & 7) * 8);
    }

    // stats: shuffle-reduce -> per-wave LDS row -> cross-wave sum -> ONE coalesced store
    #pragma unroll
    for (int t = 0; t < 4; ++t) {
        float s = 0.f, q = 0.f;
        #pragma unroll
        for (int t2 = 0; t2 < 2; ++t2)
            #pragma unroll
            for (int r2 = 0; r2 < 4; ++r2) { float v = acc[t2][t][r2]; s += v; q += v * v; }
        s += __shfl_xor(s, 16); q += __shfl_xor(q, 16);
        s += __shfl_xor(s, 32); q += __shfl_xor(q, 32);
        if (quad == 0) {
            sstat[wave][t * 16 + m16] = s;
            sstat[wave][64 + t * 16 + m16] = q;
        }
    }
    __syncthreads();
    if (tid < 128) {
        float p = sstat[0][tid] + sstat[1][tid] + sstat[2][tid] + sstat[3][tid];
        partial[(long)blockIdx.x * 128 + tid] = p;
    }
}

// ---------------- BN+ReLU in place on bf16, 8-wide ----------------
__global__ void bnrelu1_vec(unsigned short* __restrict__ x, const float* __restrict__ stats,
                            const float* __restrict__ g, const float* __restrict__ be, long n) {
    __shared__ float sc[64], sh[64];
    int tid = threadIdx.x;
    if (tid < 64) {
        float mu  = stats[tid] / (float)n;
        float var = stats[64 + tid] / (float)n - mu * mu;
        float s   = g[tid] * rsqrtf(var + EPS);
        sc[tid] = s; sh[tid] = be[tid] - mu * s;
    }
    __syncthreads();
    long i = (long)blockIdx.x * 256 + tid;
    long tot = (n + 1) * 8;
    if (i >= tot) return;
    long j = i >> 3; int c0 = (int)(i & 7) * 8;
    union { bf16x8 v; unsigned short s[8]; } u, o;
    if (j < n) {
        u.v = *(const bf16x8*)(x + j * 64 + c0);
        #pragma unroll
        for (int t = 0; t < 8; ++t) {
            float f = bf2f(u.s[t]) * sc[c0 + t] + sh[c0 + t];
            o.s[t] = f2bf(f > 0.f ? f : 0.f);
        }
    } else {
        #pragma unroll
        for (int t = 0; t < 8; ++t) o.s[t] = 0;
    }
    *(bf16x8*)(x + j * 64 + c0) = o.v;
}

// ---------------- conv_pipe: B in LDS 3-slot ring (block-shared), counted vmcnt ------
// R12/R13 verified. XCD-chunked block swizzle: with sorted rows each XCD works a
// contiguous ~2.6MB window of xin -> A-gathers become L2-resident.
template <int NT, bool BF16OUT>
__global__ __launch_bounds__(256, 2) void conv_pipe(const unsigned short* __restrict__ xin,
                                                    const unsigned short* __restrict__ Wt,
                                                    const int* __restrict__ idxG,
                                                    void* __restrict__ outv, int n,
                                                    float* __restrict__ partial) {
    constexpr int COUT = NT * 16;
    constexpr int SLICE = COUT * 64 * 2;     // 8KB (NT4) / 16KB (NT8)
    constexpr int ROUNDS = SLICE / 4096;     // stage instrs per thread per slot: 2 / 4
    __shared__ __align__(16) int lidx[4][1024];
    __shared__ __align__(16) char bbuf[3][SLICE];
    __shared__ float sstat[4][2 * COUT];

    int tid = threadIdx.x;
    int wave = tid >> 6, lane = tid & 63;
    int m16 = lane & 15, quad = lane >> 4;
    long tile = swz_bid(blockIdx.x, gridDim.x) * 4 + wave;
    long j0 = tile * 32;
    bool valid = (j0 < n);
    long jb = valid ? (j0 >> 5) : 0;

    auto stageB = [&](int k, int slot) {
        const char* src = (const char*)Wt + (long)k * SLICE;
        #pragma unroll
        for (int r = 0; r < ROUNDS; ++r)
            __builtin_amdgcn_global_load_lds(
                (const __attribute__((address_space(1))) unsigned*)(src + r * 4096 + wave * 1024 + lane * 16),
                (__attribute__((address_space(3))) unsigned*)(&bbuf[slot][r * 4096 + wave * 1024]),
                16, 0, 0);
    };

    // ---- prologue ----
    {   // idx stage: 4 instrs/wave (wave-private)
        const int* src = idxG + jb * 1024;
        #pragma unroll
        for (int i = 0; i < 4; ++i)
            __builtin_amdgcn_global_load_lds(
                (const __attribute__((address_space(1))) unsigned*)(src + i * 256 + lane * 4),
                (__attribute__((address_space(3))) unsigned*)(&lidx[wave][i * 256]),
                16, 0, 0);
    }
    stageB(0, 0);
    // retire idx (own-wave LDS write visible after vmcnt retire); keep B0 in flight
    if constexpr (ROUNDS == 2) asm volatile("s_waitcnt vmcnt(2)" ::: "memory");
    else                       asm volatile("s_waitcnt vmcnt(4)" ::: "memory");

    const int* lip = &lidx[wave][m16];
    bf16x8 ar[3][2][2];   // [ring][row-half][k-half]
    auto loadA = [&](int k, int slot) {
        int r0 = valid ? lip[k * 32] : n;
        int r1 = valid ? lip[k * 32 + 16] : n;
        const unsigned short* a0 = xin + (long)r0 * 64 + quad * 8;
        const unsigned short* a1 = xin + (long)r1 * 64 + quad * 8;
        ar[slot][0][0] = *(const bf16x8*)a0;
        ar[slot][0][1] = *(const bf16x8*)(a0 + 32);
        ar[slot][1][0] = *(const bf16x8*)a1;
        ar[slot][1][1] = *(const bf16x8*)(a1 + 32);
    };
    loadA(0, 0);
    stageB(1, 1);
    loadA(1, 1);
    // outstanding: B0:R, A0:4, B1:R, A1:4

    f32x4 acc[2][NT];
    #pragma unroll
    for (int t2 = 0; t2 < 2; ++t2)
        #pragma unroll
        for (int t = 0; t < NT; ++t) acc[t2][t] = (f32x4){0.f, 0.f, 0.f, 0.f};

    #pragma unroll
    for (int k = 0; k < KK; ++k) {
        // counted gate: retire (B(k),A(k)), keep next batch in flight
        if (k < KK - 1) {
            if constexpr (ROUNDS == 2) asm volatile("s_waitcnt vmcnt(6)" ::: "memory");
            else                       asm volatile("s_waitcnt vmcnt(8)" ::: "memory");
        } else {
            asm volatile("s_waitcnt vmcnt(0)" ::: "memory");
        }
        __builtin_amdgcn_s_barrier();            // all waves' B(k) parts resident
        __builtin_amdgcn_sched_barrier(0);
        if (k + 2 < KK) {
            stageB(k + 2, (k + 2) % 3);          // slot's old readers done pre-barrier
            loadA(k + 2, (k + 2) % 3);
        }
        const char* bs = &bbuf[k % 3][0];
        __builtin_amdgcn_s_setprio(1);
        #pragma unroll
        for (int s = 0; s < 2; ++s)
            #pragma unroll
            for (int t = 0; t < NT; ++t) {
                bf16x8 b = *(const bf16x8*)(bs + ((t * 2 + s) * 64 + lane) * 16);
                acc[0][t] = mfma16(ar[k % 3][0][s], b, acc[0][t]);
                acc[1][t] = mfma16(ar[k % 3][1][s], b, acc[1][t]);
            }
        __builtin_amdgcn_s_setprio(0);
    }

    // epilogue: staged coalesced C writes (alias wave-private lidx, dead after loop)
    asm volatile("" ::: "memory");
    if constexpr (BF16OUT) {
        unsigned short* sb = (unsigned short*)&lidx[wave][0];   // 4KB = 32 x 64 bf16
        #pragma unroll
        for (int t2 = 0; t2 < 2; ++t2)
            #pragma unroll
            for (int t = 0; t < NT; ++t)
                #pragma unroll
                for (int r2 = 0; r2 < 4; ++r2)
                    sb[(t2 * 16 + quad * 4 + r2) * 64 + t * 16 + m16] = f2bf(acc[t2][t][r2]);
        asm volatile("s_waitcnt lgkmcnt(0)" ::: "memory");
        #pragma unroll
        for (int i = 0; i < 4; ++i) {
            int row = i * 8 + (lane >> 3);
            long rr = j0 + row;
            if (rr < n)
                *(bf16x8*)((unsigned short*)outv + rr * 64 + (lane & 7) * 8) =
                    *(const bf16x8*)(sb + row * 64 + (lane & 7) * 8);
        }
        asm volatile("" ::: "memory");
    } else if constexpr (COUT == 64) {
        // 2 passes of 16 rows x 64 f32 (4KB)
        float* sb = (float*)&lidx[wave][0];
        #pragma unroll
        for (int t2 = 0; t2 < 2; ++t2) {
            #pragma unroll
            for (int t = 0; t < NT; ++t)
                #pragma unroll
                for (int r2 = 0; r2 < 4; ++r2)
                    sb[(quad * 4 + r2) * COUT + t * 16 + m16] = acc[t2][t][r2];
            asm volatile("s_waitcnt lgkmcnt(0)" ::: "memory");
            #pragma unroll
            for (int i = 0; i < 4; ++i) {
                int row = i * 4 + (lane >> 4);
                long rr = j0 + t2 * 16 + row;
                if (rr < n)
                    *(float4*)((float*)outv + rr * COUT + (lane & 15) * 4) =
                        *(const float4*)(sb + row * COUT + (lane & 15) * 4);
            }
            asm volatile("" ::: "memory");
        }
    } else {
        // COUT==128: 4 passes of 8 rows x 128 f32 (4KB); half the lanes write per pass
        float* sb = (float*)&lidx[wave][0];
        #pragma unroll
        for (int p = 0; p < 4; ++p) {
            const int t2p = p >> 1;
            const int qbase = (p & 1) * 2;          // quads {qbase, qbase+1} hold these rows
            if ((quad >> 1) == (p & 1)) {
                int lrb = (quad - qbase) * 4;       // local row base 0 or 4
                #pragma unroll
                for (int t = 0; t < NT; ++t)
                    #pragma unroll
                    for (int r2 = 0; r2 < 4; ++r2)
                        sb[(lrb + r2) * 128 + t * 16 + m16] = acc[t2p][t][r2];
            }
            asm volatile("s_waitcnt lgkmcnt(0)" ::: "memory");
            #pragma unroll
            for (int i = 0; i < 4; ++i) {
                int f = i * 64 + lane;              // float4 index within 8x128 tile
                int row = f >> 5, c4 = f & 31;
                long rr = j0 + p * 8 + row;
                if (rr < n)
                    *(float4*)((float*)outv + rr * 128 + c4 * 4) =
                        *(const float4*)(sb + row * 128 + c4 * 4);
            }
            asm volatile("" ::: "memory");
        }
    }

    // stats: shuffle-reduce -> per-wave LDS row -> cross-wave sum -> coalesced store
    #pragma unroll
    for (int t = 0; t < NT; ++t) {
        float s = 0.f, q = 0.f;
        #pragma unroll
        for (int t2 = 0; t2 < 2; ++t2)
            #pragma unroll
            for (int r2 = 0; r2 < 4; ++r2) { float v = acc[t2][t][r2]; s += v; q += v * v; }
        s += __shfl_xor(s, 16); q += __shfl_xor(q, 16);
        s += __shfl_xor(s, 32); q += __shfl_xor(q, 32);
        if (quad == 0) {
            sstat[wave][t * 16 + m16] = s;
            sstat[wave][COUT + t * 16 + m16] = q;
        }
    }
    __syncthreads();
    if (tid < 2 * COUT) {
        float p = sstat[0][tid] + sstat[1][tid] + sstat[2][tid] + sstat[3][tid];
        partial[(long)blockIdx.x * (2 * COUT) + tid] = p;
    }
}

// ---------------- sorted-segment pool: BN+ReLU+max+bf16, ZERO atomics ----------------
// Rows sorted by pool_seg -> pooled row p's sources are contiguous [ofs[p]-cnt[p], ofs[p])
// (scatter_perm turned ofs into end-pointers). One wave per pooled row; lane = channel.
// Also writes the zero pad row p==np. BN+ReLU >= 0 and segments non-empty -> init 0 ok.
__global__ void pool_sorted(const unsigned short* __restrict__ x, const float* __restrict__ stats,
                            const float* __restrict__ g, const float* __restrict__ be,
                            const int* __restrict__ ofs, const int* __restrict__ cnt,
                            long n, int np, unsigned short* __restrict__ xpn) {
    int wave = threadIdx.x >> 6, c = threadIdx.x & 63;
    long p = (long)blockIdx.x * 4 + wave;
    if (p > np) return;
    if (p == np) { xpn[p * 64 + c] = 0; return; }
    float mu  = stats[c] / (float)n;
    float var = stats[64 + c] / (float)n - mu * mu;
    float sc  = g[c] * rsqrtf(var + EPS);
    float sh  = be[c] - mu * sc;
    int e = ofs[p];
    int s = e - cnt[p];
    float m = 0.f;
    for (int r = s; r < e; ++r) {
        float v = bf2f(x[(long)r * 64 + c]) * sc + sh;
        if (v < 0.f) v = 0.f;
        if (v > m) m = v;
    }
    xpn[p * 64 + c] = f2bf(m);
}

// ---------------- final BN+ReLU in place on d_out, float4 ----------------
__global__ void bnrelu_out_vec(float* __restrict__ x, const float* __restrict__ stats,
                               const float* __restrict__ g, const float* __restrict__ be,
                               long n) {
    __shared__ float sc[128], sh[128];
    int tid = threadIdx.x;
    if (tid < 128) {
        float mu  = stats[tid] / (float)n;
        float var = stats[128 + tid] / (float)n - mu * mu;
        float s   = g[tid] * rsqrtf(var + EPS);
        sc[tid] = s; sh[tid] = be[tid] - mu * s;
    }
    __syncthreads();
    long i = (long)blockIdx.x * 256 + tid;
    long tot = n * 32;
    if (i >= tot) return;
    int c0 = (int)(i & 31) * 4;
    float4 v = ((float4*)x)[i];
    v.x = v.x * sc[c0]     + sh[c0];     v.x = v.x > 0.f ? v.x : 0.f;
    v.y = v.y * sc[c0 + 1] + sh[c0 + 1]; v.y = v.y > 0.f ? v.y : 0.f;
    v.z = v.z * sc[c0 + 2] + sh[c0 + 2]; v.z = v.z > 0.f ? v.z : 0.f;
    v.w = v.w * sc[c0 + 3] + sh[c0 + 3]; v.w = v.w > 0.f ? v.w : 0.f;
    ((float4*)x)[i] = v;
}

extern "C" void kernel_launch(void* const* d_in, const int* in_sizes, int n_in,
                              void* d_out, int out_size, void* d_ws, size_t ws_size,
                              hipStream_t stream) {
    const float* feats = (const float*)d_in[0];
    const float* W1  = (const float*)d_in[1];
    const float* g1  = (const float*)d_in[3];
    const float* be1 = (const float*)d_in[4];
    const float* W2  = (const float*)d_in[5];
    const float* g2  = (const float*)d_in[7];
    const float* be2 = (const float*)d_in[8];
    const float* W3  = (const float*)d_in[9];
    const float* g3  = (const float*)d_in[11];
    const float* be3 = (const float*)d_in[12];
    const int* km_in   = (const int*)d_in[13];
    const int* km_out  = (const int*)d_in[14];
    const int* pool_seg = (const int*)d_in[15];
    const int* km2_in  = (const int*)d_in[16];
    const int* km2_out = (const int*)d_in[17];

    const int n  = in_sizes[0];           // 160000
    const int M  = in_sizes[13] / KK;
    const int np = out_size / 128;        // N_POOL
    const int M2 = in_sizes[16] / KK;
    const long nb1 = n / 32 + 2;
    const long nb2 = np / 32 + 2;

    const int waves1 = (n + 31) / 32;
    const int nblk1  = (waves1 + 3) / 4;
    const int waves2 = (n + 31) / 32;     // conv_pipe L2: 32 rows/wave
    const int nblk2  = (waves2 + 3) / 4;
    const int waves3 = (np + 31) / 32;    // conv_pipe L3: 32 rows/wave, full 128 cols
    const int nblk3  = (waves3 + 3) / 4;

    // bias terms (b1/b2/b3) skipped: constant per-channel shift cancels through
    // training-mode BatchNorm exactly (mean-subtracted, variance unchanged).

    char* ws = (char*)d_ws;
    size_t off = 0;
    auto alloc = [&](size_t bytes) -> char* {
        char* p = ws + off;
        off += (bytes + 255) & ~(size_t)255;
        return p;
    };
    int* idxG1 = (int*)alloc(nb1 * 4096);
    int* idxG2 = (int*)alloc(nb2 * 4096);
    unsigned short* W1t = (unsigned short*)alloc(64 * 32 * 2);
    unsigned short* W2t = (unsigned short*)alloc((size_t)KK * 64 * 64 * 2);
    unsigned short* W3t = (unsigned short*)alloc((size_t)KK * 128 * 64 * 2);
    float* stats = (float*)alloc(4096);
    unsigned short* x1n = (unsigned short*)alloc((size_t)(n + 1) * 64 * 2);
    unsigned short* x2r = (unsigned short*)alloc((size_t)n * 64 * 2);
    unsigned short* xpn = (unsigned short*)alloc((size_t)(np + 1) * 64 * 2);
    float* part1 = (float*)alloc((size_t)nblk1 * 128 * 4);
    float* part2 = (float*)alloc((size_t)nblk2 * 128 * 4);
    float* part3 = (float*)alloc((size_t)nblk3 * 256 * 4);
    int* cnt  = (int*)alloc((size_t)np * 4);
    int* ofs  = (int*)alloc((size_t)np * 4);
    int* bsum = (int*)alloc(256 * 4);
    int* perm = (int*)alloc((size_t)n * 4);
    int* invp = (int*)alloc((size_t)n * 4);
    float* featp = (float*)alloc((size_t)n * 4);
    float* x3 = (float*)d_out;
    if (off > ws_size) return;

    float* stats1 = stats;
    float* stats2 = stats + 128;
    float* stats3 = stats + 256;

    hipMemsetAsync(stats, 0, 4096, stream);
    hipMemsetAsync(cnt, 0, (size_t)np * 4, stream);

    // ---- spatial sort: perm/inv by pool_seg (rank of 2x2x2 cell in flat order) ----
    {
        int nblk = (int)((n + 255) / 256);
        hist_seg<<<nblk, 256, 0, stream>>>(pool_seg, n, cnt);
        int nb = (np + 255) / 256;              // <= 256
        scan_block256<<<nb, 256, 0, stream>>>(cnt, np, ofs, bsum);
        scan_tops256<<<1, 256, 0, stream>>>(bsum, nb);
        scan_add<<<nb, 256, 0, stream>>>(ofs, bsum, np);
        scatter_perm<<<nblk, 256, 0, stream>>>(pool_seg, n, ofs, perm, invp);
        permute_f32<<<nblk, 256, 0, stream>>>(feats, perm, featp, n);
    }

    {
        long t1 = nb1 * 1024;
        fill_i32<<<(int)((t1 + 255) / 256), 256, 0, stream>>>(idxG1, t1, n);
        long t2 = nb2 * 1024;
        fill_i32<<<(int)((t2 + 255) / 256), 256, 0, stream>>>(idxG2, t2, np);
        long e1 = (long)KK * M;
        invert_map_p<<<(int)((e1 + 255) / 256), 256, 0, stream>>>(km_in, km_out, invp, idxG1, M, n);
        long e2 = (long)KK * M2;
        invert_map_g<<<(int)((e2 + 255) / 256), 256, 0, stream>>>(km2_in, km2_out, idxG2, M2, np);
    }
    {
        w1t_bf16<<<8, 256, 0, stream>>>(W1, W1t);
        long t2 = (long)KK * 64 * 64;
        wt_frag<<<(int)((t2 + 255) / 256), 256, 0, stream>>>(W2, W2t, 64, 64);
        long t3 = (long)KK * 64 * 128;
        wt_frag<<<(int)((t3 + 255) / 256), 256, 0, stream>>>(W3, W3t, 64, 128);
    }

    // layer 1 (sorted rows) + partial stats -> reduce
    conv1_mfma<<<nblk1, 256, 0, stream>>>(featp, W1t, idxG1, n, x1n, part1);
    stats_part<<<(nblk1 + 63) / 64, 128, 0, stream>>>(part1, nblk1, 128, stats1);
    {
        long tot = ((long)(n + 1) * 8 + 255) / 256;
        bnrelu1_vec<<<(int)tot, 256, 0, stream>>>(x1n, stats1, g1, be1, n);
    }
    // layer 2: B in LDS ring + XCD-chunked swizzle over sorted rows
    conv_pipe<4, true><<<nblk2, 256, 0, stream>>>(x1n, W2t, idxG1, x2r, n, part2);
    stats_part<<<(nblk2 + 63) / 64, 128, 0, stream>>>(part2, nblk2, 128, stats2);
    // sorted-segment pool (BN+ReLU+max fused, no atomics, writes pad row too)
    {
        int pblk = (np + 1 + 3) / 4;
        pool_sorted<<<pblk, 256, 0, stream>>>(x2r, stats2, g2, be2, ofs, cnt, n, np, xpn);
    }
    // layer 3: B in LDS ring, full 128 cols/wave + partial stats -> reduce
    conv_pipe<8, false><<<nblk3, 256, 0, stream>>>(xpn, W3t, idxG2, x3, np, part3);
    stats_part<<<(nblk3 + 63) / 64, 256, 0, stream>>>(part3, nblk3, 256, stats3);
    {
        long tot = ((long)np * 32 + 255) / 256;
        bnrelu_out_vec<<<(int)tot, 256, 0, stream>>>(x3, stats3, g3, be3, np);
    }
}

// Round 16
// 374.482 us; speedup vs baseline: 1.1034x; 1.1034x over previous
//
#include <hip/hip_runtime.h>

#define EPS 1e-5f
#define KK 27

typedef __bf16 bf16x8 __attribute__((ext_vector_type(8)));
typedef float f32x4 __attribute__((ext_vector_type(4)));

__device__ __forceinline__ unsigned short f2bf(float f) {
    union { float f; unsigned u; } v; v.f = f;
    unsigned r = v.u + 0x7fffu + ((v.u >> 16) & 1u);  // round-to-nearest-even
    return (unsigned short)(r >> 16);
}
__device__ __forceinline__ float bf2f(unsigned short h) {
    union { unsigned u; float f; } v; v.u = ((unsigned)h) << 16; return v.f;
}

__device__ __forceinline__ f32x4 mfma16(bf16x8 a, bf16x8 b, f32x4 c) {
    return __builtin_amdgcn_mfma_f32_16x16x32_bf16(a, b, c, 0, 0, 0);
}

// ---------------- map build: idxG[block][k][row&31] ----------------
__global__ void fill_i32(int* __restrict__ p, long tot, int val) {
    long i = (long)blockIdx.x * blockDim.x + threadIdx.x;
    if (i < tot) p[i] = val;
}

__global__ void invert_map_g(const int* __restrict__ km_in, const int* __restrict__ km_out,
                             int* __restrict__ idxG, int M, int nrows) {
    long i = (long)blockIdx.x * blockDim.x + threadIdx.x;
    if (i >= (long)KK * M) return;
    int k = (int)(i / M);
    int ki = km_in[i];
    if (ki < nrows) {
        int ko = km_out[i];
        idxG[(long)(ko >> 5) * 1024 + k * 32 + (ko & 31)] = ki;
    }
}

// ---------------- weight prep ----------------
__global__ void wt_frag(const float* __restrict__ W, unsigned short* __restrict__ Wt,
                        int Cin, int Cout) {
    long i = (long)blockIdx.x * blockDim.x + threadIdx.x;
    long tot = (long)KK * Cin * Cout;
    if (i >= tot) return;
    int k  = (int)(i / (Cin * Cout));
    int r  = (int)(i % (Cin * Cout));
    int ci = r / Cout, co = r % Cout;
    int t = co >> 4, m16 = co & 15;
    int s = ci >> 5, quad = (ci >> 3) & 3, j = ci & 7;
    int lane = quad * 16 + m16;
    long off = ((((long)k * (Cout >> 4) + t) * 2 + s) * 64 + lane) * 8 + j;
    Wt[off] = f2bf(W[i]);
}

__global__ void w1t_bf16(const float* __restrict__ W1, unsigned short* __restrict__ W1t) {
    int i = blockIdx.x * blockDim.x + threadIdx.x;
    if (i >= 64 * 32) return;
    int c = i / 32, kk = i % 32;
    W1t[i] = (kk < KK) ? f2bf(W1[kk * 64 + c]) : (unsigned short)0;
}

// ---------------- partial-stats reduction: sum 64 block-rows, few spread atomics ----
__global__ void stats_part(const float* __restrict__ p, int nblk, int width,
                           float* __restrict__ out) {
    int c = threadIdx.x;               // < width
    int b0 = blockIdx.x * 64;
    int b1 = b0 + 64 < nblk ? b0 + 64 : nblk;
    float acc = 0.f;
    for (int b = b0; b < b1; ++b) acc += p[(long)b * width + c];
    atomicAdd(&out[c], acc);
}

// ---------------- conv1 gather-MFMA (1->64): block-partial stats, coalesced C ----
__global__ __launch_bounds__(256, 2) void conv1_mfma(const float* __restrict__ feats,
                                                     const unsigned short* __restrict__ W1t,
                                                     const int* __restrict__ idxG, int n,
                                                     unsigned short* __restrict__ out,
                                                     float* __restrict__ partial) {
    __shared__ __align__(16) int lidx[4][1024];
    __shared__ float sstat[4][128];
    int tid = threadIdx.x;
    int wave = tid >> 6, lane = tid & 63;
    int m16 = lane & 15, quad = lane >> 4;
    long tile = (long)blockIdx.x * 4 + wave;
    long j0 = tile * 32;
    bool valid = (j0 < n);
    long jb = valid ? (j0 >> 5) : 0;

    // stage this wave's 27x32 idx block (4KB, one coalesced wave-load x4)
    {
        const int* src = idxG + jb * 1024;
        #pragma unroll
        for (int i = 0; i < 4; ++i)
            __builtin_amdgcn_global_load_lds(
                (const __attribute__((address_space(1))) unsigned*)(src + i * 256 + lane * 4),
                (__attribute__((address_space(3))) unsigned*)(&lidx[wave][i * 256]),
                16, 0, 0);
    }
    asm volatile("s_waitcnt vmcnt(0)" ::: "memory");
    const int* lip = &lidx[wave][0];

    int idx[2][8];
    #pragma unroll
    for (int i = 0; i < 8; ++i) {
        int kk = quad * 8 + i;
        bool kv = (kk < KK);
        idx[0][i] = (valid && kv) ? lip[kk * 32 + m16] : n;
        idx[1][i] = (valid && kv) ? lip[kk * 32 + 16 + m16] : n;
    }
    float f[2][8];
    #pragma unroll
    for (int i = 0; i < 8; ++i)
        #pragma unroll
        for (int t2 = 0; t2 < 2; ++t2) {
            int r = idx[t2][i];
            f[t2][i] = (r < n) ? feats[r] : 0.f;
        }

    union { bf16x8 v; unsigned short s[8]; } a[2];
    #pragma unroll
    for (int t2 = 0; t2 < 2; ++t2)
        #pragma unroll
        for (int i = 0; i < 8; ++i) a[t2].s[i] = f2bf(f[t2][i]);

    f32x4 acc[2][4];
    #pragma unroll
    for (int t2 = 0; t2 < 2; ++t2)
        #pragma unroll
        for (int t = 0; t < 4; ++t) acc[t2][t] = (f32x4){0.f, 0.f, 0.f, 0.f};

    const unsigned short* wb = W1t + quad * 8;
    #pragma unroll
    for (int t = 0; t < 4; ++t) {
        bf16x8 b = *(const bf16x8*)(wb + (t * 16 + m16) * 32);
        acc[0][t] = mfma16(a[0].v, b, acc[0][t]);
        acc[1][t] = mfma16(a[1].v, b, acc[1][t]);
    }

    // staged coalesced C-store: acc -> LDS (alias idx area, dead now) -> 128B rows
    asm volatile("" ::: "memory");
    unsigned short* sb = (unsigned short*)&lidx[wave][0];   // 4KB = 32 rows x 64 bf16
    #pragma unroll
    for (int t2 = 0; t2 < 2; ++t2)
        #pragma unroll
        for (int t = 0; t < 4; ++t)
            #pragma unroll
            for (int r2 = 0; r2 < 4; ++r2)
                sb[(t2 * 16 + quad * 4 + r2) * 64 + t * 16 + m16] = f2bf(acc[t2][t][r2]);
    asm volatile("s_waitcnt lgkmcnt(0)" ::: "memory");
    #pragma unroll
    for (int i = 0; i < 4; ++i) {
        int row = i * 8 + (lane >> 3);
        long rr = j0 + row;
        if (rr < n)
            *(bf16x8*)(out + rr * 64 + (lane & 7) * 8) =
                *(const bf16x8*)(sb + row * 64 + (lane & 7) * 8);
    }

    // stats: shuffle-reduce -> per-wave LDS row -> cross-wave sum -> ONE coalesced store
    #pragma unroll
    for (int t = 0; t < 4; ++t) {
        float s = 0.f, q = 0.f;
        #pragma unroll
        for (int t2 = 0; t2 < 2; ++t2)
            #pragma unroll
            for (int r2 = 0; r2 < 4; ++r2) { float v = acc[t2][t][r2]; s += v; q += v * v; }
        s += __shfl_xor(s, 16); q += __shfl_xor(q, 16);
        s += __shfl_xor(s, 32); q += __shfl_xor(q, 32);
        if (quad == 0) {
            sstat[wave][t * 16 + m16] = s;
            sstat[wave][64 + t * 16 + m16] = q;
        }
    }
    __syncthreads();
    if (tid < 128) {
        float p = sstat[0][tid] + sstat[1][tid] + sstat[2][tid] + sstat[3][tid];
        partial[(long)blockIdx.x * 128 + tid] = p;
    }
}

// ---------------- BN+ReLU in place on bf16, 8-wide ----------------
__global__ void bnrelu1_vec(unsigned short* __restrict__ x, const float* __restrict__ stats,
                            const float* __restrict__ g, const float* __restrict__ be, long n) {
    __shared__ float sc[64], sh[64];
    int tid = threadIdx.x;
    if (tid < 64) {
        float mu  = stats[tid] / (float)n;
        float var = stats[64 + tid] / (float)n - mu * mu;
        float s   = g[tid] * rsqrtf(var + EPS);
        sc[tid] = s; sh[tid] = be[tid] - mu * s;
    }
    __syncthreads();
    long i = (long)blockIdx.x * 256 + tid;
    long tot = (n + 1) * 8;
    if (i >= tot) return;
    long j = i >> 3; int c0 = (int)(i & 7) * 8;
    union { bf16x8 v; unsigned short s[8]; } u, o;
    if (j < n) {
        u.v = *(const bf16x8*)(x + j * 64 + c0);
        #pragma unroll
        for (int t = 0; t < 8; ++t) {
            float f = bf2f(u.s[t]) * sc[c0 + t] + sh[c0 + t];
            o.s[t] = f2bf(f > 0.f ? f : 0.f);
        }
    } else {
        #pragma unroll
        for (int t = 0; t < 8; ++t) o.s[t] = 0;
    }
    *(bf16x8*)(x + j * 64 + c0) = o.v;
}

// ---------------- conv_pipe: B in LDS 3-slot ring (block-shared), counted vmcnt ------
// R12/R13 verified structure. NEW: sstat aliased into bbuf[0] (dead after the K-loop;
// last bbuf[0] reads were iter 24, fenced by barriers 25/26; iter-26 reads hit
// bbuf[2], disjoint). NT4 LDS: 16K lidx + 24K bbuf = 40960 B -> exactly 4 blocks/CU.
template <int NT, bool BF16OUT>
__global__ __launch_bounds__(256, 2) void conv_pipe(const unsigned short* __restrict__ xin,
                                                    const unsigned short* __restrict__ Wt,
                                                    const int* __restrict__ idxG,
                                                    void* __restrict__ outv, int n,
                                                    float* __restrict__ partial) {
    constexpr int COUT = NT * 16;
    constexpr int SLICE = COUT * 64 * 2;     // 8KB (NT4) / 16KB (NT8)
    constexpr int ROUNDS = SLICE / 4096;     // stage instrs per thread per slot: 2 / 4
    __shared__ __align__(16) int lidx[4][1024];
    __shared__ __align__(16) char bbuf[3][SLICE];

    int tid = threadIdx.x;
    int wave = tid >> 6, lane = tid & 63;
    int m16 = lane & 15, quad = lane >> 4;
    long tile = (long)blockIdx.x * 4 + wave;
    long j0 = tile * 32;
    bool valid = (j0 < n);
    long jb = valid ? (j0 >> 5) : 0;

    auto stageB = [&](int k, int slot) {
        const char* src = (const char*)Wt + (long)k * SLICE;
        #pragma unroll
        for (int r = 0; r < ROUNDS; ++r)
            __builtin_amdgcn_global_load_lds(
                (const __attribute__((address_space(1))) unsigned*)(src + r * 4096 + wave * 1024 + lane * 16),
                (__attribute__((address_space(3))) unsigned*)(&bbuf[slot][r * 4096 + wave * 1024]),
                16, 0, 0);
    };

    // ---- prologue ----
    {   // idx stage: 4 instrs/wave (wave-private)
        const int* src = idxG + jb * 1024;
        #pragma unroll
        for (int i = 0; i < 4; ++i)
            __builtin_amdgcn_global_load_lds(
                (const __attribute__((address_space(1))) unsigned*)(src + i * 256 + lane * 4),
                (__attribute__((address_space(3))) unsigned*)(&lidx[wave][i * 256]),
                16, 0, 0);
    }
    stageB(0, 0);
    // retire idx (own-wave LDS write visible after vmcnt retire); keep B0 in flight
    if constexpr (ROUNDS == 2) asm volatile("s_waitcnt vmcnt(2)" ::: "memory");
    else                       asm volatile("s_waitcnt vmcnt(4)" ::: "memory");

    const int* lip = &lidx[wave][m16];
    bf16x8 ar[3][2][2];   // [ring][row-half][k-half]
    auto loadA = [&](int k, int slot) {
        int r0 = valid ? lip[k * 32] : n;
        int r1 = valid ? lip[k * 32 + 16] : n;
        const unsigned short* a0 = xin + (long)r0 * 64 + quad * 8;
        const unsigned short* a1 = xin + (long)r1 * 64 + quad * 8;
        ar[slot][0][0] = *(const bf16x8*)a0;
        ar[slot][0][1] = *(const bf16x8*)(a0 + 32);
        ar[slot][1][0] = *(const bf16x8*)a1;
        ar[slot][1][1] = *(const bf16x8*)(a1 + 32);
    };
    loadA(0, 0);
    stageB(1, 1);
    loadA(1, 1);
    // outstanding: B0:R, A0:4, B1:R, A1:4

    f32x4 acc[2][NT];
    #pragma unroll
    for (int t2 = 0; t2 < 2; ++t2)
        #pragma unroll
        for (int t = 0; t < NT; ++t) acc[t2][t] = (f32x4){0.f, 0.f, 0.f, 0.f};

    #pragma unroll
    for (int k = 0; k < KK; ++k) {
        // counted gate: retire (B(k),A(k)), keep next batch in flight
        if (k < KK - 1) {
            if constexpr (ROUNDS == 2) asm volatile("s_waitcnt vmcnt(6)" ::: "memory");
            else                       asm volatile("s_waitcnt vmcnt(8)" ::: "memory");
        } else {
            asm volatile("s_waitcnt vmcnt(0)" ::: "memory");
        }
        __builtin_amdgcn_s_barrier();            // all waves' B(k) parts resident
        __builtin_amdgcn_sched_barrier(0);
        if (k + 2 < KK) {
            stageB(k + 2, (k + 2) % 3);          // slot's old readers done pre-barrier
            loadA(k + 2, (k + 2) % 3);
        }
        const char* bs = &bbuf[k % 3][0];
        __builtin_amdgcn_s_setprio(1);
        #pragma unroll
        for (int s = 0; s < 2; ++s)
            #pragma unroll
            for (int t = 0; t < NT; ++t) {
                bf16x8 b = *(const bf16x8*)(bs + ((t * 2 + s) * 64 + lane) * 16);
                acc[0][t] = mfma16(ar[k % 3][0][s], b, acc[0][t]);
                acc[1][t] = mfma16(ar[k % 3][1][s], b, acc[1][t]);
            }
        __builtin_amdgcn_s_setprio(0);
    }

    // epilogue: staged coalesced C writes (alias wave-private lidx, dead after loop)
    asm volatile("" ::: "memory");
    if constexpr (BF16OUT) {
        unsigned short* sb = (unsigned short*)&lidx[wave][0];   // 4KB = 32 x 64 bf16
        #pragma unroll
        for (int t2 = 0; t2 < 2; ++t2)
            #pragma unroll
            for (int t = 0; t < NT; ++t)
                #pragma unroll
                for (int r2 = 0; r2 < 4; ++r2)
                    sb[(t2 * 16 + quad * 4 + r2) * 64 + t * 16 + m16] = f2bf(acc[t2][t][r2]);
        asm volatile("s_waitcnt lgkmcnt(0)" ::: "memory");
        #pragma unroll
        for (int i = 0; i < 4; ++i) {
            int row = i * 8 + (lane >> 3);
            long rr = j0 + row;
            if (rr < n)
                *(bf16x8*)((unsigned short*)outv + rr * 64 + (lane & 7) * 8) =
                    *(const bf16x8*)(sb + row * 64 + (lane & 7) * 8);
        }
        asm volatile("" ::: "memory");
    } else if constexpr (COUT == 64) {
        // 2 passes of 16 rows x 64 f32 (4KB)
        float* sb = (float*)&lidx[wave][0];
        #pragma unroll
        for (int t2 = 0; t2 < 2; ++t2) {
            #pragma unroll
            for (int t = 0; t < NT; ++t)
                #pragma unroll
                for (int r2 = 0; r2 < 4; ++r2)
                    sb[(quad * 4 + r2) * COUT + t * 16 + m16] = acc[t2][t][r2];
            asm volatile("s_waitcnt lgkmcnt(0)" ::: "memory");
            #pragma unroll
            for (int i = 0; i < 4; ++i) {
                int row = i * 4 + (lane >> 4);
                long rr = j0 + t2 * 16 + row;
                if (rr < n)
                    *(float4*)((float*)outv + rr * COUT + (lane & 15) * 4) =
                        *(const float4*)(sb + row * COUT + (lane & 15) * 4);
            }
            asm volatile("" ::: "memory");
        }
    } else {
        // COUT==128: 4 passes of 8 rows x 128 f32 (4KB); half the lanes write per pass
        float* sb = (float*)&lidx[wave][0];
        #pragma unroll
        for (int p = 0; p < 4; ++p) {
            const int t2p = p >> 1;
            const int qbase = (p & 1) * 2;          // quads {qbase, qbase+1} hold these rows
            if ((quad >> 1) == (p & 1)) {
                int lrb = (quad - qbase) * 4;       // local row base 0 or 4
                #pragma unroll
                for (int t = 0; t < NT; ++t)
                    #pragma unroll
                    for (int r2 = 0; r2 < 4; ++r2)
                        sb[(lrb + r2) * 128 + t * 16 + m16] = acc[t2p][t][r2];
            }
            asm volatile("s_waitcnt lgkmcnt(0)" ::: "memory");
            #pragma unroll
            for (int i = 0; i < 4; ++i) {
                int f = i * 64 + lane;              // float4 index within 8x128 tile
                int row = f >> 5, c4 = f & 31;
                long rr = j0 + p * 8 + row;
                if (rr < n)
                    *(float4*)((float*)outv + rr * 128 + c4 * 4) =
                        *(const float4*)(sb + row * 128 + c4 * 4);
            }
            asm volatile("" ::: "memory");
        }
    }

    // stats: shuffle-reduce -> per-wave row in bbuf[0] (dead after loop; iter-26 reads
    // hit bbuf[2], disjoint) -> syncthreads -> cross-wave sum -> coalesced store
    float* sst = (float*)&bbuf[0][0];               // [4][2*COUT] floats <= SLICE
    #pragma unroll
    for (int t = 0; t < NT; ++t) {
        float s = 0.f, q = 0.f;
        #pragma unroll
        for (int t2 = 0; t2 < 2; ++t2)
            #pragma unroll
            for (int r2 = 0; r2 < 4; ++r2) { float v = acc[t2][t][r2]; s += v; q += v * v; }
        s += __shfl_xor(s, 16); q += __shfl_xor(q, 16);
        s += __shfl_xor(s, 32); q += __shfl_xor(q, 32);
        if (quad == 0) {
            sst[wave * 2 * COUT + t * 16 + m16] = s;
            sst[wave * 2 * COUT + COUT + t * 16 + m16] = q;
        }
    }
    __syncthreads();
    if (tid < 2 * COUT) {
        float p = sst[0 * 2 * COUT + tid] + sst[1 * 2 * COUT + tid] +
                  sst[2 * 2 * COUT + tid] + sst[3 * 2 * COUT + tid];
        partial[(long)blockIdx.x * (2 * COUT) + tid] = p;
    }
}

// ---------------- BN+ReLU on bf16 fused with segment-max pool ----------------
__global__ void pool_kernel(const unsigned short* __restrict__ x, const float* __restrict__ stats,
                            const float* __restrict__ g, const float* __restrict__ be,
                            const int* __restrict__ seg, long n, unsigned* __restrict__ pooled) {
    long j = (long)blockIdx.x * 4 + threadIdx.y;
    if (j >= n) return;
    int c = threadIdx.x;
    float mu  = stats[c] / (float)n;
    float var = stats[64 + c] / (float)n - mu * mu;
    float rs  = rsqrtf(var + EPS);
    float v   = g[c] * (bf2f(x[j * 64 + c]) - mu) * rs + be[c];
    if (v < 0.f) v = 0.f;
    atomicMax(&pooled[(long)seg[j] * 64 + c], __float_as_uint(v));
}

__global__ void pooled_bf16_vec(const unsigned* __restrict__ pooled, long np,
                                unsigned short* __restrict__ out) {
    long i = (long)blockIdx.x * 256 + threadIdx.x;
    long tot = (np + 1) * 8;
    if (i >= tot) return;
    long j = i >> 3; int c0 = (int)(i & 7) * 8;
    union { bf16x8 v; unsigned short s[8]; } o;
    if (j < np) {
        #pragma unroll
        for (int t = 0; t < 8; ++t)
            o.s[t] = f2bf(__uint_as_float(pooled[j * 64 + c0 + t]));
    } else {
        #pragma unroll
        for (int t = 0; t < 8; ++t) o.s[t] = 0;
    }
    *(bf16x8*)(out + j * 64 + c0) = o.v;
}

// ---------------- final BN+ReLU in place on d_out, float4 ----------------
__global__ void bnrelu_out_vec(float* __restrict__ x, const float* __restrict__ stats,
                               const float* __restrict__ g, const float* __restrict__ be,
                               long n) {
    __shared__ float sc[128], sh[128];
    int tid = threadIdx.x;
    if (tid < 128) {
        float mu  = stats[tid] / (float)n;
        float var = stats[128 + tid] / (float)n - mu * mu;
        float s   = g[tid] * rsqrtf(var + EPS);
        sc[tid] = s; sh[tid] = be[tid] - mu * s;
    }
    __syncthreads();
    long i = (long)blockIdx.x * 256 + tid;
    long tot = n * 32;
    if (i >= tot) return;
    int c0 = (int)(i & 31) * 4;
    float4 v = ((float4*)x)[i];
    v.x = v.x * sc[c0]     + sh[c0];     v.x = v.x > 0.f ? v.x : 0.f;
    v.y = v.y * sc[c0 + 1] + sh[c0 + 1]; v.y = v.y > 0.f ? v.y : 0.f;
    v.z = v.z * sc[c0 + 2] + sh[c0 + 2]; v.z = v.z > 0.f ? v.z : 0.f;
    v.w = v.w * sc[c0 + 3] + sh[c0 + 3]; v.w = v.w > 0.f ? v.w : 0.f;
    ((float4*)x)[i] = v;
}

extern "C" void kernel_launch(void* const* d_in, const int* in_sizes, int n_in,
                              void* d_out, int out_size, void* d_ws, size_t ws_size,
                              hipStream_t stream) {
    const float* feats = (const float*)d_in[0];
    const float* W1  = (const float*)d_in[1];
    const float* g1  = (const float*)d_in[3];
    const float* be1 = (const float*)d_in[4];
    const float* W2  = (const float*)d_in[5];
    const float* g2  = (const float*)d_in[7];
    const float* be2 = (const float*)d_in[8];
    const float* W3  = (const float*)d_in[9];
    const float* g3  = (const float*)d_in[11];
    const float* be3 = (const float*)d_in[12];
    const int* km_in   = (const int*)d_in[13];
    const int* km_out  = (const int*)d_in[14];
    const int* pool_seg = (const int*)d_in[15];
    const int* km2_in  = (const int*)d_in[16];
    const int* km2_out = (const int*)d_in[17];

    const int n  = in_sizes[0];           // 160000
    const int M  = in_sizes[13] / KK;
    const int np = out_size / 128;        // N_POOL
    const int M2 = in_sizes[16] / KK;
    const long nb1 = n / 32 + 2;
    const long nb2 = np / 32 + 2;

    const int waves1 = (n + 31) / 32;
    const int nblk1  = (waves1 + 3) / 4;
    const int waves2 = (n + 31) / 32;     // conv_pipe L2: 32 rows/wave
    const int nblk2  = (waves2 + 3) / 4;
    const int waves3 = (np + 31) / 32;    // conv_pipe L3: 32 rows/wave, full 128 cols
    const int nblk3  = (waves3 + 3) / 4;

    // bias terms (b1/b2/b3) skipped: constant per-channel shift cancels through
    // training-mode BatchNorm exactly (mean-subtracted, variance unchanged).

    char* ws = (char*)d_ws;
    size_t off = 0;
    auto alloc = [&](size_t bytes) -> char* {
        char* p = ws + off;
        off += (bytes + 255) & ~(size_t)255;
        return p;
    };
    int* idxG1 = (int*)alloc(nb1 * 4096);
    int* idxG2 = (int*)alloc(nb2 * 4096);
    unsigned short* W1t = (unsigned short*)alloc(64 * 32 * 2);
    unsigned short* W2t = (unsigned short*)alloc((size_t)KK * 64 * 64 * 2);
    unsigned short* W3t = (unsigned short*)alloc((size_t)KK * 128 * 64 * 2);
    float* stats = (float*)alloc(4096);
    unsigned short* x1n = (unsigned short*)alloc((size_t)(n + 1) * 64 * 2);
    unsigned short* x2r = (unsigned short*)alloc((size_t)n * 64 * 2);
    unsigned* pooled = (unsigned*)alloc((size_t)np * 64 * 4);
    unsigned short* xpn = (unsigned short*)alloc((size_t)(np + 1) * 64 * 2);
    float* part1 = (float*)alloc((size_t)nblk1 * 128 * 4);
    float* part2 = (float*)alloc((size_t)nblk2 * 128 * 4);
    float* part3 = (float*)alloc((size_t)nblk3 * 256 * 4);
    float* x3 = (float*)d_out;
    if (off > ws_size) return;

    float* stats1 = stats;
    float* stats2 = stats + 128;
    float* stats3 = stats + 256;

    hipMemsetAsync(stats, 0, 4096, stream);
    hipMemsetAsync(pooled, 0, (size_t)np * 64 * 4, stream);

    {
        long t1 = nb1 * 1024;
        fill_i32<<<(int)((t1 + 255) / 256), 256, 0, stream>>>(idxG1, t1, n);
        long t2 = nb2 * 1024;
        fill_i32<<<(int)((t2 + 255) / 256), 256, 0, stream>>>(idxG2, t2, np);
        long e1 = (long)KK * M;
        invert_map_g<<<(int)((e1 + 255) / 256), 256, 0, stream>>>(km_in, km_out, idxG1, M, n);
        long e2 = (long)KK * M2;
        invert_map_g<<<(int)((e2 + 255) / 256), 256, 0, stream>>>(km2_in, km2_out, idxG2, M2, np);
    }
    {
        w1t_bf16<<<8, 256, 0, stream>>>(W1, W1t);
        long t2 = (long)KK * 64 * 64;
        wt_frag<<<(int)((t2 + 255) / 256), 256, 0, stream>>>(W2, W2t, 64, 64);
        long t3 = (long)KK * 64 * 128;
        wt_frag<<<(int)((t3 + 255) / 256), 256, 0, stream>>>(W3, W3t, 64, 128);
    }

    // layer 1 + partial stats -> reduce
    conv1_mfma<<<nblk1, 256, 0, stream>>>(feats, W1t, idxG1, n, x1n, part1);
    stats_part<<<(nblk1 + 63) / 64, 128, 0, stream>>>(part1, nblk1, 128, stats1);
    {
        long tot = ((long)(n + 1) * 8 + 255) / 256;
        bnrelu1_vec<<<(int)tot, 256, 0, stream>>>(x1n, stats1, g1, be1, n);
    }
    // layer 2: B in LDS ring (block-shared), 32 rows/wave + partial stats -> reduce
    conv_pipe<4, true><<<nblk2, 256, 0, stream>>>(x1n, W2t, idxG1, x2r, n, part2);
    stats_part<<<(nblk2 + 63) / 64, 128, 0, stream>>>(part2, nblk2, 128, stats2);
    pool_kernel<<<(n + 3) / 4, dim3(64, 4), 0, stream>>>(x2r, stats2, g2, be2, pool_seg, n, pooled);
    {
        long tot = ((long)(np + 1) * 8 + 255) / 256;
        pooled_bf16_vec<<<(int)tot, 256, 0, stream>>>(pooled, np, xpn);
    }
    // layer 3: B in LDS ring, full 128 cols/wave + partial stats -> reduce
    conv_pipe<8, false><<<nblk3, 256, 0, stream>>>(xpn, W3t, idxG2, x3, np, part3);
    stats_part<<<(nblk3 + 63) / 64, 256, 0, stream>>>(part3, nblk3, 256, stats3);
    {
        long tot = ((long)np * 32 + 255) / 256;
        bnrelu_out_vec<<<(int)tot, 256, 0, stream>>>(x3, stats3, g3, be3, np);
    }
}